// Round 1
// baseline (707.725 us; speedup 1.0000x reference)
//
#include <hip/hip_runtime.h>

#define S_LEN 2048
#define DHEAD 64
#define NQT   32                      // S / 64
#define SCALE_LOG2E 0.18033688011112042f   // (1/sqrt(64)) * log2(e)

typedef __bf16 bf16_t;
typedef bf16_t bf16x8 __attribute__((ext_vector_type(8)));
typedef bf16_t bf16x4 __attribute__((ext_vector_type(4)));
typedef float  f32x4  __attribute__((ext_vector_type(4)));

static __device__ __forceinline__ f32x4 mfma16(bf16x8 a, bf16x8 b, f32x4 c) {
    return __builtin_amdgcn_mfma_f32_16x16x32_bf16(a, b, c, 0, 0, 0);
}

// swizzled byte offset into a [64][64] bf16 tile (128B row stride)
static __device__ __forceinline__ int sw(int row, int colByte) {
    return (row << 7) + (colByte ^ ((row & 7) << 4));
}

// stage a 64x64 fp32 tile (row-major, stride 64) -> swizzled bf16 LDS tile
template <bool SCALE>
static __device__ __forceinline__ void stage_tile(const float* __restrict__ src,
                                                  char* dst, int tid) {
#pragma unroll
    for (int i = 0; i < 2; ++i) {
        int f = tid + (i << 8);          // 0..511, 8 floats each
        int r = f >> 3;
        int c = (f & 7) << 3;            // element col
        const f32x4* sp = (const f32x4*)(src + r * 64 + c);
        f32x4 a = sp[0], b = sp[1];
        if (SCALE) { a = a * SCALE_LOG2E; b = b * SCALE_LOG2E; }
        bf16x8 v;
        v[0] = (bf16_t)a[0]; v[1] = (bf16_t)a[1]; v[2] = (bf16_t)a[2]; v[3] = (bf16_t)a[3];
        v[4] = (bf16_t)b[0]; v[5] = (bf16_t)b[1]; v[6] = (bf16_t)b[2]; v[7] = (bf16_t)b[3];
        *(bf16x8*)(dst + sw(r, c << 1)) = v;
    }
}

// stage a 64x64 fp32 V tile transposed -> swizzled bf16 Vt[d][k] LDS tile
static __device__ __forceinline__ void stage_vt(const float* __restrict__ src,
                                                char* dst, int tid) {
    int k0 = (tid >> 4) << 2;
    int d0 = (tid & 15) << 2;
    f32x4 r0 = *(const f32x4*)(src + (k0 + 0) * 64 + d0);
    f32x4 r1 = *(const f32x4*)(src + (k0 + 1) * 64 + d0);
    f32x4 r2 = *(const f32x4*)(src + (k0 + 2) * 64 + d0);
    f32x4 r3 = *(const f32x4*)(src + (k0 + 3) * 64 + d0);
#pragma unroll
    for (int j = 0; j < 4; ++j) {
        int d = d0 + j;
        bf16x4 w;
        w[0] = (bf16_t)r0[j]; w[1] = (bf16_t)r1[j];
        w[2] = (bf16_t)r2[j]; w[3] = (bf16_t)r3[j];
        *(bf16x4*)(dst + (d << 7) + ((k0 << 1) ^ ((d & 7) << 4))) = w;
    }
}

extern "C" __global__ void __launch_bounds__(256)
attn_fused(const float* __restrict__ Q, const float* __restrict__ K,
           const float* __restrict__ V, float* __restrict__ out,
           float* __restrict__ att) {
    __shared__ __align__(16) char QsB[8192];
    __shared__ __align__(16) char KsB[8192];
    __shared__ __align__(16) char VtB[8192];
    __shared__ __align__(16) char PsB[4][2048];

    const int tid  = threadIdx.x;
    const int bid  = blockIdx.x;
    const int bh   = bid & 31;            // B*H = 32
    const int qt   = 31 - (bid >> 5);     // heavy (causal-deep) blocks first
    const int lane = tid & 63;
    const int wq   = tid >> 6;            // wave id 0..3
    const int g    = lane >> 4;           // quarter-wave group
    const int qc   = lane & 15;

    const size_t hoff = (size_t)bh * (S_LEN * DHEAD);
    const float* Qb = Q + hoff;
    const float* Kb = K + hoff;
    const float* Vb = V + hoff;
    float* outb = out + hoff;
    float* attb = att + (size_t)bh * ((size_t)S_LEN * S_LEN);

    const int q0 = qt << 6;

    // ---- zero the masked (upper-triangle) attention region ----
    {
        f32x4 z = {0.f, 0.f, 0.f, 0.f};
        for (int zt = qt + 1; zt < NQT; ++zt) {
            float* base = attb + (size_t)q0 * S_LEN + (zt << 6);
#pragma unroll
            for (int i = 0; i < 4; ++i) {
                int f = tid + (i << 8);
                int r = f >> 4;
                int c = (f & 15) << 2;
                __builtin_nontemporal_store(z, (f32x4*)(base + (size_t)r * S_LEN + c));
            }
        }
    }

    // ---- stage Q tile (pre-scaled into log2 domain), load B-fragments ----
    stage_tile<true>(Qb + q0 * DHEAD, QsB, tid);
    __syncthreads();

    const int qrow = (wq << 4) + qc;      // q row within block tile
    const int qg   = q0 + qrow;           // global q row
    bf16x8 bq0 = *(const bf16x8*)(QsB + sw(qrow, (g << 4)));
    bf16x8 bq1 = *(const bf16x8*)(QsB + sw(qrow, 64 + (g << 4)));

    const int nkt = qt + 1;
    float m = -1e30f, l = 0.f;

    // ================= pass 1: row max + sumexp =================
    for (int kt = 0; kt < nkt; ++kt) {
        __syncthreads();
        stage_tile<false>(Kb + kt * 4096, KsB, tid);
        __syncthreads();
        float sv[16];
#pragma unroll
        for (int kb = 0; kb < 4; ++kb) {
            const int ar = (kb << 4) + qc;      // key row within tile
            bf16x8 a0 = *(const bf16x8*)(KsB + sw(ar, (g << 4)));
            bf16x8 a1 = *(const bf16x8*)(KsB + sw(ar, 64 + (g << 4)));
            f32x4 acc = {0.f, 0.f, 0.f, 0.f};
            acc = mfma16(a0, bq0, acc);
            acc = mfma16(a1, bq1, acc);
#pragma unroll
            for (int r = 0; r < 4; ++r) sv[(kb << 2) + r] = acc[r];
        }
        if (kt == qt) {   // diagonal tile: causal mask
#pragma unroll
            for (int kb = 0; kb < 4; ++kb)
#pragma unroll
                for (int r = 0; r < 4; ++r) {
                    int kg = (kt << 6) + (kb << 4) + (g << 2) + r;
                    if (kg > qg) sv[(kb << 2) + r] = -1e30f;
                }
        }
        float mx = sv[0];
#pragma unroll
        for (int i = 1; i < 16; ++i) mx = fmaxf(mx, sv[i]);
        mx = fmaxf(mx, __shfl_xor(mx, 16));
        mx = fmaxf(mx, __shfl_xor(mx, 32));
        float mn = fmaxf(m, mx);
        float corr = exp2f(m - mn);
        float se = 0.f;
#pragma unroll
        for (int i = 0; i < 16; ++i) se += exp2f(sv[i] - mn);
        se += __shfl_xor(se, 16);
        se += __shfl_xor(se, 32);
        l = l * corr + se;
        m = mn;
    }

    const float il = 1.0f / l;
    f32x4 oacc[4];
#pragma unroll
    for (int i = 0; i < 4; ++i) oacc[i] = (f32x4){0.f, 0.f, 0.f, 0.f};

    char* PsW = PsB[wq];

    // ========= pass 2: recompute scores, write P, accumulate O = P·V =========
    for (int kt = 0; kt < nkt; ++kt) {
        __syncthreads();
        stage_tile<false>(Kb + kt * 4096, KsB, tid);
        stage_vt(Vb + kt * 4096, VtB, tid);
        __syncthreads();
#pragma unroll
        for (int kb = 0; kb < 4; ++kb) {
            const int ar = (kb << 4) + qc;
            bf16x8 a0 = *(const bf16x8*)(KsB + sw(ar, (g << 4)));
            bf16x8 a1 = *(const bf16x8*)(KsB + sw(ar, 64 + (g << 4)));
            f32x4 acc = {0.f, 0.f, 0.f, 0.f};
            acc = mfma16(a0, bq0, acc);
            acc = mfma16(a1, bq1, acc);
            float p[4];
#pragma unroll
            for (int r = 0; r < 4; ++r) {
                float s = acc[r];
                if (kt == qt) {
                    int kg = (kt << 6) + (kb << 4) + (g << 2) + r;
                    if (kg > qg) s = -1e30f;
                }
                p[r] = exp2f(s - m) * il;
            }
            f32x4 pw = {p[0], p[1], p[2], p[3]};
            __builtin_nontemporal_store(
                pw, (f32x4*)(attb + (size_t)qg * S_LEN + (kt << 6) + (kb << 4) + (g << 2)));
            bf16x4 pb;
            pb[0] = (bf16_t)p[0]; pb[1] = (bf16_t)p[1];
            pb[2] = (bf16_t)p[2]; pb[3] = (bf16_t)p[3];
            *(bf16x4*)(PsW + (qc << 7) + (((kb << 5) + (g << 3)) ^ ((qc & 7) << 4))) = pb;
        }
        // PV: O^T[d][q] += V^T[d][k] · P^T[k][q]
        bf16x8 bp0 = *(const bf16x8*)(PsW + sw(qc, (g << 4)));
        bf16x8 bp1 = *(const bf16x8*)(PsW + sw(qc, 64 + (g << 4)));
#pragma unroll
        for (int dc = 0; dc < 4; ++dc) {
            const int vr = (dc << 4) + qc;
            bf16x8 av0 = *(const bf16x8*)(VtB + sw(vr, (g << 4)));
            bf16x8 av1 = *(const bf16x8*)(VtB + sw(vr, 64 + (g << 4)));
            oacc[dc] = mfma16(av0, bp0, oacc[dc]);
            oacc[dc] = mfma16(av1, bp1, oacc[dc]);
        }
    }

    // ---- write O (already normalized since P was normalized) ----
#pragma unroll
    for (int dc = 0; dc < 4; ++dc) {
        f32x4 o = {oacc[dc][0], oacc[dc][1], oacc[dc][2], oacc[dc][3]};
        *(f32x4*)(outb + (size_t)qg * DHEAD + (dc << 4) + (g << 2)) = o;
    }
}

extern "C" void kernel_launch(void* const* d_in, const int* in_sizes, int n_in,
                              void* d_out, int out_size, void* d_ws, size_t ws_size,
                              hipStream_t stream) {
    const float* Q = (const float*)d_in[0];
    const float* K = (const float*)d_in[1];
    const float* V = (const float*)d_in[2];
    // d_out = output (B*H*S*D floats) ++ attention (B*H*S*S floats)
    float* out = (float*)d_out;
    float* att = out + (size_t)2 * 16 * S_LEN * DHEAD;
    dim3 grid(2 * 16 * NQT);   // 1024 blocks: (b,h) x 32 q-tiles, heavy first
    dim3 block(256);
    hipLaunchKernelGGL(attn_fused, grid, block, 0, stream, Q, K, V, out, att);
}

// Round 3
// 677.749 us; speedup vs baseline: 1.0442x; 1.0442x over previous
//
#include <hip/hip_runtime.h>

#define S_LEN 2048
#define DHEAD 64
#define NQT   32                      // S / 64
#define BH    32                      // B*H
#define SCALE_LOG2E 0.18033688011112042f   // (1/sqrt(64)) * log2(e)

typedef __bf16 bf16_t;
typedef bf16_t bf16x8 __attribute__((ext_vector_type(8)));
typedef bf16_t bf16x4 __attribute__((ext_vector_type(4)));
typedef float  f32x4  __attribute__((ext_vector_type(4)));

static __device__ __forceinline__ f32x4 mfma16(bf16x8 a, bf16x8 b, f32x4 c) {
    return __builtin_amdgcn_mfma_f32_16x16x32_bf16(a, b, c, 0, 0, 0);
}

// swizzled byte offset into a [64][64] bf16 tile (128B row stride)
static __device__ __forceinline__ int sw(int row, int colByte) {
    return (row << 7) + (colByte ^ ((row & 7) << 4));
}

// stage a 64x64 fp32 tile (row-major, stride 64) -> swizzled bf16 LDS tile
template <bool SCALE>
static __device__ __forceinline__ void stage_tile(const float* __restrict__ src,
                                                  char* dst, int tid) {
#pragma unroll
    for (int i = 0; i < 2; ++i) {
        int f = tid + (i << 8);          // 0..511, 8 floats each
        int r = f >> 3;
        int c = (f & 7) << 3;            // element col
        const f32x4* sp = (const f32x4*)(src + r * 64 + c);
        f32x4 a = sp[0], b = sp[1];
        if (SCALE) { a = a * SCALE_LOG2E; b = b * SCALE_LOG2E; }
        bf16x8 v;
        v[0] = (bf16_t)a[0]; v[1] = (bf16_t)a[1]; v[2] = (bf16_t)a[2]; v[3] = (bf16_t)a[3];
        v[4] = (bf16_t)b[0]; v[5] = (bf16_t)b[1]; v[6] = (bf16_t)b[2]; v[7] = (bf16_t)b[3];
        *(bf16x8*)(dst + sw(r, c << 1)) = v;
    }
}

// stage a 64x64 fp32 V tile transposed -> swizzled bf16 Vt[d][k] LDS tile
static __device__ __forceinline__ void stage_vt(const float* __restrict__ src,
                                                char* dst, int tid) {
    int k0 = (tid >> 4) << 2;
    int d0 = (tid & 15) << 2;
    f32x4 r0 = *(const f32x4*)(src + (k0 + 0) * 64 + d0);
    f32x4 r1 = *(const f32x4*)(src + (k0 + 1) * 64 + d0);
    f32x4 r2 = *(const f32x4*)(src + (k0 + 2) * 64 + d0);
    f32x4 r3 = *(const f32x4*)(src + (k0 + 3) * 64 + d0);
#pragma unroll
    for (int j = 0; j < 4; ++j) {
        int d = d0 + j;
        bf16x4 w;
        w[0] = (bf16_t)r0[j]; w[1] = (bf16_t)r1[j];
        w[2] = (bf16_t)r2[j]; w[3] = (bf16_t)r3[j];
        *(bf16x4*)(dst + (d << 7) + ((k0 << 1) ^ ((d & 7) << 4))) = w;
    }
}

// ============ Kernel A: causal flash fwd -> O, per-row (m, 1/l) ============
extern "C" __global__ void __launch_bounds__(256)
attn_flash(const float* __restrict__ Q, const float* __restrict__ K,
           const float* __restrict__ V, float* __restrict__ out,
           float* __restrict__ mrow, float* __restrict__ ilrow) {
    __shared__ __align__(16) char QsB[8192];
    __shared__ __align__(16) char KsB[8192];
    __shared__ __align__(16) char VtB[8192];
    __shared__ __align__(16) char PsB[4][2048];

    const int tid  = threadIdx.x;
    const int bid  = blockIdx.x;
    const int bh   = bid & 31;
    const int qt   = 31 - (bid >> 5);     // heavy (causal-deep) q-tiles first
    const int lane = tid & 63;
    const int wq   = tid >> 6;
    const int g    = lane >> 4;
    const int qc   = lane & 15;

    const size_t hoff = (size_t)bh * (S_LEN * DHEAD);
    const float* Qb = Q + hoff;
    const float* Kb = K + hoff;
    const float* Vb = V + hoff;
    float* outb = out + hoff;

    const int q0 = qt << 6;

    stage_tile<true>(Qb + q0 * DHEAD, QsB, tid);
    __syncthreads();

    const int qrow = (wq << 4) + qc;
    const int qg   = q0 + qrow;
    bf16x8 bq0 = *(const bf16x8*)(QsB + sw(qrow, (g << 4)));
    bf16x8 bq1 = *(const bf16x8*)(QsB + sw(qrow, 64 + (g << 4)));

    float m = -1e30f, l = 0.f;
    f32x4 oacc[4];
#pragma unroll
    for (int i = 0; i < 4; ++i) oacc[i] = (f32x4){0.f, 0.f, 0.f, 0.f};

    char* PsW = PsB[wq];

    for (int kt = 0; kt <= qt; ++kt) {
        __syncthreads();
        stage_tile<false>(Kb + kt * 4096, KsB, tid);
        stage_vt(Vb + kt * 4096, VtB, tid);
        __syncthreads();

        float sv[16];
#pragma unroll
        for (int kb = 0; kb < 4; ++kb) {
            const int ar = (kb << 4) + qc;
            bf16x8 a0 = *(const bf16x8*)(KsB + sw(ar, (g << 4)));
            bf16x8 a1 = *(const bf16x8*)(KsB + sw(ar, 64 + (g << 4)));
            f32x4 acc = {0.f, 0.f, 0.f, 0.f};
            acc = mfma16(a0, bq0, acc);
            acc = mfma16(a1, bq1, acc);
#pragma unroll
            for (int r = 0; r < 4; ++r) sv[(kb << 2) + r] = acc[r];
        }
        if (kt == qt) {
#pragma unroll
            for (int kb = 0; kb < 4; ++kb)
#pragma unroll
                for (int r = 0; r < 4; ++r) {
                    int kg = (kt << 6) + (kb << 4) + (g << 2) + r;
                    if (kg > qg) sv[(kb << 2) + r] = -1e30f;
                }
        }
        float mx = sv[0];
#pragma unroll
        for (int i = 1; i < 16; ++i) mx = fmaxf(mx, sv[i]);
        mx = fmaxf(mx, __shfl_xor(mx, 16));
        mx = fmaxf(mx, __shfl_xor(mx, 32));
        const float mn   = fmaxf(m, mx);
        const float corr = exp2f(m - mn);

        float p[16], se = 0.f;
#pragma unroll
        for (int i = 0; i < 16; ++i) { p[i] = exp2f(sv[i] - mn); se += p[i]; }
        se += __shfl_xor(se, 16);
        se += __shfl_xor(se, 32);
        l = l * corr + se;
        m = mn;
#pragma unroll
        for (int i = 0; i < 4; ++i) oacc[i] = oacc[i] * corr;

        // pack p -> per-wave LDS (bf16, swizzled), then PV MFMA
#pragma unroll
        for (int kb = 0; kb < 4; ++kb) {
            bf16x4 pb;
            pb[0] = (bf16_t)p[(kb << 2) + 0]; pb[1] = (bf16_t)p[(kb << 2) + 1];
            pb[2] = (bf16_t)p[(kb << 2) + 2]; pb[3] = (bf16_t)p[(kb << 2) + 3];
            *(bf16x4*)(PsW + (qc << 7) + (((kb << 5) + (g << 3)) ^ ((qc & 7) << 4))) = pb;
        }
        bf16x8 bp0 = *(const bf16x8*)(PsW + sw(qc, (g << 4)));
        bf16x8 bp1 = *(const bf16x8*)(PsW + sw(qc, 64 + (g << 4)));
#pragma unroll
        for (int dc = 0; dc < 4; ++dc) {
            const int vr = (dc << 4) + qc;
            bf16x8 av0 = *(const bf16x8*)(VtB + sw(vr, (g << 4)));
            bf16x8 av1 = *(const bf16x8*)(VtB + sw(vr, 64 + (g << 4)));
            oacc[dc] = mfma16(av0, bp0, oacc[dc]);
            oacc[dc] = mfma16(av1, bp1, oacc[dc]);
        }
    }

    const float il = 1.0f / l;
#pragma unroll
    for (int dc = 0; dc < 4; ++dc) {
        f32x4 o = oacc[dc] * il;
        *(f32x4*)(outb + (size_t)qg * DHEAD + (dc << 4) + (g << 2)) = o;
    }
    if (g == 0) {
        mrow [bh * S_LEN + qg] = m;
        ilrow[bh * S_LEN + qg] = il;
    }
}

// ============ Kernel B: one block per 64x64 att tile ============
extern "C" __global__ void __launch_bounds__(256)
attn_probs(const float* __restrict__ Q, const float* __restrict__ K,
           const float* __restrict__ mrow, const float* __restrict__ ilrow,
           float* __restrict__ att) {
    const int tid = threadIdx.x;
    const int bid = blockIdx.x;
    const int bh  = bid >> 10;
    const int qt  = (bid >> 5) & 31;
    const int kt  = bid & 31;

    float* attb = att + (size_t)bh * ((size_t)S_LEN * S_LEN);
    const int q0 = qt << 6;
    const int k0 = kt << 6;

    if (kt > qt) {   // masked-out tile: stream zeros
        f32x4 z = {0.f, 0.f, 0.f, 0.f};
#pragma unroll
        for (int i = 0; i < 4; ++i) {
            int f = tid + (i << 8);
            int r = f >> 4;
            int c = (f & 15) << 2;
            __builtin_nontemporal_store(z, (f32x4*)(attb + (size_t)(q0 + r) * S_LEN + k0 + c));
        }
        return;
    }

    __shared__ __align__(16) char QsB[8192];
    __shared__ __align__(16) char KsB[8192];

    const size_t hoff = (size_t)bh * (S_LEN * DHEAD);
    stage_tile<true >(Q + hoff + q0 * DHEAD, QsB, tid);
    stage_tile<false>(K + hoff + k0 * DHEAD, KsB, tid);
    __syncthreads();

    const int lane = tid & 63;
    const int wq   = tid >> 6;
    const int g    = lane >> 4;
    const int qc   = lane & 15;
    const int qrow = (wq << 4) + qc;
    const int qg   = q0 + qrow;

    bf16x8 bq0 = *(const bf16x8*)(QsB + sw(qrow, (g << 4)));
    bf16x8 bq1 = *(const bf16x8*)(QsB + sw(qrow, 64 + (g << 4)));

    const float m  = mrow [bh * S_LEN + qg];
    const float il = ilrow[bh * S_LEN + qg];

#pragma unroll
    for (int kb = 0; kb < 4; ++kb) {
        const int ar = (kb << 4) + qc;
        bf16x8 a0 = *(const bf16x8*)(KsB + sw(ar, (g << 4)));
        bf16x8 a1 = *(const bf16x8*)(KsB + sw(ar, 64 + (g << 4)));
        f32x4 acc = {0.f, 0.f, 0.f, 0.f};
        acc = mfma16(a0, bq0, acc);
        acc = mfma16(a1, bq1, acc);
        f32x4 pw;
#pragma unroll
        for (int r = 0; r < 4; ++r) {
            int kg = k0 + (kb << 4) + (g << 2) + r;
            float p = exp2f(acc[r] - m) * il;
            pw[r] = (kt == qt && kg > qg) ? 0.f : p;
        }
        __builtin_nontemporal_store(
            pw, (f32x4*)(attb + (size_t)qg * S_LEN + k0 + (kb << 4) + (g << 2)));
    }
}

extern "C" void kernel_launch(void* const* d_in, const int* in_sizes, int n_in,
                              void* d_out, int out_size, void* d_ws, size_t ws_size,
                              hipStream_t stream) {
    const float* Q = (const float*)d_in[0];
    const float* K = (const float*)d_in[1];
    const float* V = (const float*)d_in[2];
    float* out = (float*)d_out;
    float* att = out + (size_t)BH * S_LEN * DHEAD;
    float* mrow  = (float*)d_ws;                 // BH*S floats
    float* ilrow = mrow + (size_t)BH * S_LEN;    // BH*S floats

    hipLaunchKernelGGL(attn_flash, dim3(BH * NQT), dim3(256), 0, stream,
                       Q, K, V, out, mrow, ilrow);
    hipLaunchKernelGGL(attn_probs, dim3(BH * NQT * NQT), dim3(256), 0, stream,
                       Q, K, mrow, ilrow, att);
}

// Round 4
// 623.045 us; speedup vs baseline: 1.1359x; 1.0878x over previous
//
#include <hip/hip_runtime.h>

#define S_LEN 2048
#define DHEAD 64
#define NQT   32                      // S / 64
#define BH    32                      // B*H
#define SCALE_LOG2E 0.18033688011112042f   // (1/sqrt(64)) * log2(e)

typedef __bf16 bf16_t;
typedef bf16_t bf16x8 __attribute__((ext_vector_type(8)));
typedef bf16_t bf16x4 __attribute__((ext_vector_type(4)));
typedef float  f32x4  __attribute__((ext_vector_type(4)));

static __device__ __forceinline__ f32x4 mfma16(bf16x8 a, bf16x8 b, f32x4 c) {
    return __builtin_amdgcn_mfma_f32_16x16x32_bf16(a, b, c, 0, 0, 0);
}

// swizzled byte offset into a [64][64] bf16 tile (128B row stride)
static __device__ __forceinline__ int sw(int row, int colByte) {
    return (row << 7) + (colByte ^ ((row & 7) << 4));
}

// stage a 64x64 fp32 tile (row-major, stride 64) -> swizzled bf16 LDS tile
template <bool SCALE>
static __device__ __forceinline__ void stage_tile(const float* __restrict__ src,
                                                  char* dst, int tid) {
#pragma unroll
    for (int i = 0; i < 2; ++i) {
        int f = tid + (i << 8);          // 0..511, 8 floats each
        int r = f >> 3;
        int c = (f & 7) << 3;            // element col
        const f32x4* sp = (const f32x4*)(src + r * 64 + c);
        f32x4 a = sp[0], b = sp[1];
        if (SCALE) { a = a * SCALE_LOG2E; b = b * SCALE_LOG2E; }
        bf16x8 v;
        v[0] = (bf16_t)a[0]; v[1] = (bf16_t)a[1]; v[2] = (bf16_t)a[2]; v[3] = (bf16_t)a[3];
        v[4] = (bf16_t)b[0]; v[5] = (bf16_t)b[1]; v[6] = (bf16_t)b[2]; v[7] = (bf16_t)b[3];
        *(bf16x8*)(dst + sw(r, c << 1)) = v;
    }
}

// ============ Kernel A: causal flash fwd -> O, per-row (m, 1/l) ============
extern "C" __global__ void __launch_bounds__(256)
attn_flash(const float* __restrict__ Q, const float* __restrict__ K,
           const float* __restrict__ V, float* __restrict__ out,
           float* __restrict__ mrow, float* __restrict__ ilrow) {
    __shared__ __align__(16) char QsB[8192];
    __shared__ __align__(16) char KsB[8192];
    __shared__ __align__(16) char VtB[8192];
    __shared__ __align__(16) char PsB[4][2048];

    const int tid  = threadIdx.x;
    const int bid  = blockIdx.x;
    const int bh   = bid & 31;
    const int qt   = 31 - (bid >> 5);     // heavy (causal-deep) q-tiles first
    const int lane = tid & 63;
    const int wq   = tid >> 6;
    const int g    = lane >> 4;
    const int qc   = lane & 15;

    const size_t hoff = (size_t)bh * (S_LEN * DHEAD);
    const float* Qb = Q + hoff;
    const float* Kb = K + hoff;
    const float* Vb = V + hoff;
    float* outb = out + hoff;

    const int q0 = qt << 6;

    stage_tile<true>(Qb + q0 * DHEAD, QsB, tid);
    __syncthreads();

    const int qrow = (wq << 4) + qc;
    const int qg   = q0 + qrow;
    bf16x8 bq0 = *(const bf16x8*)(QsB + sw(qrow, (g << 4)));
    bf16x8 bq1 = *(const bf16x8*)(QsB + sw(qrow, 64 + (g << 4)));

    float m = -1e30f, l = 0.f;
    f32x4 oacc[4];
#pragma unroll
    for (int i = 0; i < 4; ++i) oacc[i] = (f32x4){0.f, 0.f, 0.f, 0.f};

    char* PsW = PsB[wq];

    // --- register staging (T14 async split): K tile (4xf32x4) + V tile (4xf32x4)
    const int kr_r  = tid >> 3;            // K stage rows for this thread
    const int kr_c  = (tid & 7) << 3;
    const int vk0   = (tid >> 4) << 2;     // V stage: 4 rows, 4 cols
    const int vd0   = (tid & 15) << 2;
    f32x4 kr0a, kr0b, kr1a, kr1b, vr0, vr1, vr2, vr3;

#define LOAD_TILE_REGS(kt_)                                                   \
    {                                                                         \
        const float* ks_ = Kb + (kt_) * 4096;                                 \
        kr0a = *(const f32x4*)(ks_ + kr_r * 64 + kr_c);                       \
        kr0b = *(const f32x4*)(ks_ + kr_r * 64 + kr_c + 4);                   \
        kr1a = *(const f32x4*)(ks_ + (kr_r + 32) * 64 + kr_c);                \
        kr1b = *(const f32x4*)(ks_ + (kr_r + 32) * 64 + kr_c + 4);            \
        const float* vs_ = Vb + (kt_) * 4096;                                 \
        vr0 = *(const f32x4*)(vs_ + (vk0 + 0) * 64 + vd0);                    \
        vr1 = *(const f32x4*)(vs_ + (vk0 + 1) * 64 + vd0);                    \
        vr2 = *(const f32x4*)(vs_ + (vk0 + 2) * 64 + vd0);                    \
        vr3 = *(const f32x4*)(vs_ + (vk0 + 3) * 64 + vd0);                    \
    }

    LOAD_TILE_REGS(0)

    for (int kt = 0; kt <= qt; ++kt) {
        // regs -> LDS (bf16, swizzled); LDS free per end-of-prev-iter barrier
        {
            bf16x8 v;
            v[0] = (bf16_t)kr0a[0]; v[1] = (bf16_t)kr0a[1]; v[2] = (bf16_t)kr0a[2]; v[3] = (bf16_t)kr0a[3];
            v[4] = (bf16_t)kr0b[0]; v[5] = (bf16_t)kr0b[1]; v[6] = (bf16_t)kr0b[2]; v[7] = (bf16_t)kr0b[3];
            *(bf16x8*)(KsB + sw(kr_r, kr_c << 1)) = v;
            v[0] = (bf16_t)kr1a[0]; v[1] = (bf16_t)kr1a[1]; v[2] = (bf16_t)kr1a[2]; v[3] = (bf16_t)kr1a[3];
            v[4] = (bf16_t)kr1b[0]; v[5] = (bf16_t)kr1b[1]; v[6] = (bf16_t)kr1b[2]; v[7] = (bf16_t)kr1b[3];
            *(bf16x8*)(KsB + sw(kr_r + 32, kr_c << 1)) = v;
#pragma unroll
            for (int j = 0; j < 4; ++j) {
                int d = vd0 + j;
                bf16x4 w;
                w[0] = (bf16_t)vr0[j]; w[1] = (bf16_t)vr1[j];
                w[2] = (bf16_t)vr2[j]; w[3] = (bf16_t)vr3[j];
                *(bf16x4*)(VtB + (d << 7) + ((vk0 << 1) ^ ((d & 7) << 4))) = w;
            }
        }
        __syncthreads();
        if (kt < qt) LOAD_TILE_REGS(kt + 1)   // overlaps with compute below

        float sv[16];
#pragma unroll
        for (int kb = 0; kb < 4; ++kb) {
            const int ar = (kb << 4) + qc;
            bf16x8 a0 = *(const bf16x8*)(KsB + sw(ar, (g << 4)));
            bf16x8 a1 = *(const bf16x8*)(KsB + sw(ar, 64 + (g << 4)));
            f32x4 acc = {0.f, 0.f, 0.f, 0.f};
            acc = mfma16(a0, bq0, acc);
            acc = mfma16(a1, bq1, acc);
#pragma unroll
            for (int r = 0; r < 4; ++r) sv[(kb << 2) + r] = acc[r];
        }
        if (kt == qt) {
#pragma unroll
            for (int kb = 0; kb < 4; ++kb)
#pragma unroll
                for (int r = 0; r < 4; ++r) {
                    int kg = (kt << 6) + (kb << 4) + (g << 2) + r;
                    if (kg > qg) sv[(kb << 2) + r] = -1e30f;
                }
        }
        float mx = sv[0];
#pragma unroll
        for (int i = 1; i < 16; ++i) mx = fmaxf(mx, sv[i]);
        mx = fmaxf(mx, __shfl_xor(mx, 16));
        mx = fmaxf(mx, __shfl_xor(mx, 32));
        const float mn   = fmaxf(m, mx);
        const float corr = exp2f(m - mn);

        float p[16], se = 0.f;
#pragma unroll
        for (int i = 0; i < 16; ++i) { p[i] = exp2f(sv[i] - mn); se += p[i]; }
        se += __shfl_xor(se, 16);
        se += __shfl_xor(se, 32);
        l = l * corr + se;
        m = mn;
#pragma unroll
        for (int i = 0; i < 4; ++i) oacc[i] = oacc[i] * corr;

        // pack p -> per-wave LDS (bf16, swizzled), then PV MFMA
#pragma unroll
        for (int kb = 0; kb < 4; ++kb) {
            bf16x4 pb;
            pb[0] = (bf16_t)p[(kb << 2) + 0]; pb[1] = (bf16_t)p[(kb << 2) + 1];
            pb[2] = (bf16_t)p[(kb << 2) + 2]; pb[3] = (bf16_t)p[(kb << 2) + 3];
            *(bf16x4*)(PsW + (qc << 7) + (((kb << 5) + (g << 3)) ^ ((qc & 7) << 4))) = pb;
        }
        bf16x8 bp0 = *(const bf16x8*)(PsW + sw(qc, (g << 4)));
        bf16x8 bp1 = *(const bf16x8*)(PsW + sw(qc, 64 + (g << 4)));
#pragma unroll
        for (int dc = 0; dc < 4; ++dc) {
            const int vr = (dc << 4) + qc;
            bf16x8 av0 = *(const bf16x8*)(VtB + sw(vr, (g << 4)));
            bf16x8 av1 = *(const bf16x8*)(VtB + sw(vr, 64 + (g << 4)));
            oacc[dc] = mfma16(av0, bp0, oacc[dc]);
            oacc[dc] = mfma16(av1, bp1, oacc[dc]);
        }
        __syncthreads();   // LDS consumed; next iter may overwrite
    }

    const float il = 1.0f / l;
#pragma unroll
    for (int dc = 0; dc < 4; ++dc) {
        f32x4 o = oacc[dc] * il;
        *(f32x4*)(outb + (size_t)qg * DHEAD + (dc << 4) + (g << 2)) = o;
    }
    if (g == 0) {
        mrow [bh * S_LEN + qg] = m;
        ilrow[bh * S_LEN + qg] = il;
    }
}

// ============ Kernel B: one block per 64x64 att tile ============
extern "C" __global__ void __launch_bounds__(256)
attn_probs(const float* __restrict__ Q, const float* __restrict__ K,
           const float* __restrict__ mrow, const float* __restrict__ ilrow,
           float* __restrict__ att) {
    const int tid = threadIdx.x;
    const int bid = blockIdx.x;
    const int bh  = bid >> 10;
    const int qt  = (bid >> 5) & 31;
    const int kt  = bid & 31;

    float* attb = att + (size_t)bh * ((size_t)S_LEN * S_LEN);
    const int q0 = qt << 6;
    const int k0 = kt << 6;

    if (kt > qt) {   // masked-out tile: stream zeros (16-lane contiguous runs)
        f32x4 z = {0.f, 0.f, 0.f, 0.f};
#pragma unroll
        for (int i = 0; i < 4; ++i) {
            int f = tid + (i << 8);
            int r = f >> 4;
            int c = (f & 15) << 2;
            __builtin_nontemporal_store(z, (f32x4*)(attb + (size_t)(q0 + r) * S_LEN + k0 + c));
        }
        return;
    }

    __shared__ __align__(16) char QsB[8192];
    __shared__ __align__(16) char KsB[8192];
    __shared__ __align__(16) float Pt[4096];   // 64x64 fp32, XOR-swizzled

    const size_t hoff = (size_t)bh * (S_LEN * DHEAD);
    stage_tile<true >(Q + hoff + q0 * DHEAD, QsB, tid);
    stage_tile<false>(K + hoff + k0 * DHEAD, KsB, tid);
    __syncthreads();

    const int lane = tid & 63;
    const int wq   = tid >> 6;
    const int g    = lane >> 4;
    const int qc   = lane & 15;
    const int qrow = (wq << 4) + qc;
    const int qg   = q0 + qrow;

    bf16x8 bq0 = *(const bf16x8*)(QsB + sw(qrow, (g << 4)));
    bf16x8 bq1 = *(const bf16x8*)(QsB + sw(qrow, 64 + (g << 4)));

    const float m  = mrow [bh * S_LEN + qg];
    const float il = ilrow[bh * S_LEN + qg];

#pragma unroll
    for (int kb = 0; kb < 4; ++kb) {
        const int ar = (kb << 4) + qc;
        bf16x8 a0 = *(const bf16x8*)(KsB + sw(ar, (g << 4)));
        bf16x8 a1 = *(const bf16x8*)(KsB + sw(ar, 64 + (g << 4)));
        f32x4 acc = {0.f, 0.f, 0.f, 0.f};
        acc = mfma16(a0, bq0, acc);
        acc = mfma16(a1, bq1, acc);
        f32x4 pw;
#pragma unroll
        for (int r = 0; r < 4; ++r) {
            int kg = k0 + (kb << 4) + (g << 2) + r;
            float p = exp2f(acc[r] - m) * il;
            pw[r] = (kt == qt && kg > qg) ? 0.f : p;
        }
        // -> swizzled LDS tile (float-index XOR keeps 16B granules, spreads banks)
        int colf = (kb << 4) + (g << 2);
        *(f32x4*)&Pt[(qrow << 6) + (colf ^ ((qrow & 7) << 2))] = pw;
    }
    __syncthreads();

    // coalesced store: 16 consecutive lanes cover one full 256B tile row
#pragma unroll
    for (int i = 0; i < 4; ++i) {
        int row  = (i << 4) + (tid >> 4);
        int colf = (tid & 15) << 2;
        f32x4 v = *(const f32x4*)&Pt[(row << 6) + (colf ^ ((row & 7) << 2))];
        __builtin_nontemporal_store(
            v, (f32x4*)(attb + (size_t)(q0 + row) * S_LEN + k0 + colf));
    }
}

extern "C" void kernel_launch(void* const* d_in, const int* in_sizes, int n_in,
                              void* d_out, int out_size, void* d_ws, size_t ws_size,
                              hipStream_t stream) {
    const float* Q = (const float*)d_in[0];
    const float* K = (const float*)d_in[1];
    const float* V = (const float*)d_in[2];
    float* out = (float*)d_out;
    float* att = out + (size_t)BH * S_LEN * DHEAD;
    float* mrow  = (float*)d_ws;                 // BH*S floats
    float* ilrow = mrow + (size_t)BH * S_LEN;    // BH*S floats

    hipLaunchKernelGGL(attn_flash, dim3(BH * NQT), dim3(256), 0, stream,
                       Q, K, V, out, mrow, ilrow);
    hipLaunchKernelGGL(attn_probs, dim3(BH * NQT * NQT), dim3(256), 0, stream,
                       Q, K, mrow, ilrow, att);
}